// Round 7
// baseline (49.720 us; speedup 1.0000x reference)
//
#include <hip/hip_runtime.h>

// PosFeatureLayer: out[b,m,d] = emb[b,m,d] + (m < num[b] ? feat(pts[b, idx[b,m]]) . W[:,d] : 0)
// Round-6: two-pass. Pass 1 precomputes per-row f4 features into ws (2 MB, mask
// folded in). Pass 2 is a pure homogeneous stream: emb f32x4 + uniform feat
// broadcast + FMA + nt store. No shuffles/gathers/divs in the 268 MB stream.

typedef float f32x4 __attribute__((ext_vector_type(4)));

#define DD 256  // fast path: D == 256 (64 lanes x f32x4)

// ---------------- Pass 1: per-row features (B*M threads) ----------------
__global__ __launch_bounds__(256) void posfeat_feat_kernel(
    const int* __restrict__ num,              // [B]
    const float* __restrict__ pts,            // [B,N,5]
    const int* __restrict__ indeces,          // [B,M] flat
    const int* __restrict__ image_shape,      // [4] int32 (b,c,H,W)
    f32x4* __restrict__ feat,                 // [B*M] out
    int M, int N, int total)
{
    const int gid = blockIdx.x * 256 + threadIdx.x;
    if (gid >= total) return;
    const int b = gid / M;
    const int m = gid - b * M;

    const float h = (float)image_shape[2];
    const float w = (float)image_shape[3];
    const float inv_s  = 1.0f / (fmaxf(w, h) * 0.7f);
    const float cx = w * 0.5f, cy = h * 0.5f;
    const float lscale = sqrtf(w * w + h * h) * 0.7f;
    const float inv_l  = 1.0f / lscale;
    const float half_l = lscale * 0.5f;
    const float inv_a  = 1.0f / 126.0f;

    f32x4 f = {0.f, 0.f, 0.f, 0.f};
    if (m < num[b]) {
        const int idx = indeces[gid];
        const float* p = pts + ((long long)b * N + (long long)idx) * 5;
        f.x = (p[0] - cx) * inv_s;
        f.y = (p[1] - cy) * inv_s;
        f.z = (p[4] - 45.0f) * inv_a;
        f.w = (p[3] - half_l) * inv_l;
    }
    feat[gid] = f;
}

// ---------------- Pass 2: pure stream (8 rows/wave/iter) ----------------
__global__ __launch_bounds__(256) void posfeat_stream_kernel(
    const float* __restrict__ emb,            // [B*M, DD] flat
    const f32x4* __restrict__ feat,           // [B*M]
    const float* __restrict__ W,              // [4,DD]
    float* __restrict__ out,                  // [B*M, DD] flat
    int total_tiles)                          // B*M/8
{
    const int lane = threadIdx.x & 63;
    const int wave = threadIdx.x >> 6;                  // 4 waves/block
    const int stride = gridDim.x * 4;
    const int d0 = lane * 4;

    // W fragment in registers (L1-hit, once per wave)
    const f32x4 w0 = *(const f32x4*)(W + 0 * DD + d0);
    const f32x4 w1 = *(const f32x4*)(W + 1 * DD + d0);
    const f32x4 w2 = *(const f32x4*)(W + 2 * DD + d0);
    const f32x4 w3 = *(const f32x4*)(W + 3 * DD + d0);

    for (int tile = blockIdx.x * 4 + wave; tile < total_tiles; tile += stride) {
        const long long base = (long long)tile * 8;     // first row of tile

        f32x4 e[8], f[8];
        #pragma unroll
        for (int r = 0; r < 8; ++r)
            e[r] = *(const f32x4*)(emb + (base + r) * DD + d0);
        #pragma unroll
        for (int r = 0; r < 8; ++r)
            f[r] = feat[base + r];                      // uniform addr -> broadcast

        #pragma unroll
        for (int r = 0; r < 8; ++r) {
            f32x4 o;
            o.x = e[r].x + f[r].x * w0.x + f[r].y * w1.x + f[r].z * w2.x + f[r].w * w3.x;
            o.y = e[r].y + f[r].x * w0.y + f[r].y * w1.y + f[r].z * w2.y + f[r].w * w3.y;
            o.z = e[r].z + f[r].x * w0.z + f[r].y * w1.z + f[r].z * w2.z + f[r].w * w3.z;
            o.w = e[r].w + f[r].x * w0.w + f[r].y * w1.w + f[r].z * w2.w + f[r].w * w3.w;
            __builtin_nontemporal_store(o, (f32x4*)(out + (base + r) * DD + d0));
        }
    }
}

// ---------------- Generic fallback (any D multiple of 4) ----------------
__global__ __launch_bounds__(256) void posfeat_generic_kernel(
    const float* __restrict__ emb, const int* __restrict__ num,
    const float* __restrict__ pts, const int* __restrict__ indeces,
    const int* __restrict__ image_shape, const float* __restrict__ W,
    float* __restrict__ out, int B, int M, int N, int D)
{
    const int lane = threadIdx.x & 63;
    const int wave = threadIdx.x >> 6;
    const int m = blockIdx.x * 4 + wave;
    const int b = blockIdx.y;
    if (m >= M) return;
    const float h = (float)image_shape[2];
    const float w = (float)image_shape[3];
    const float inv_s = 1.0f / (fmaxf(w, h) * 0.7f);
    const float cx = w * 0.5f, cy = h * 0.5f;
    const float lscale = sqrtf(w * w + h * h) * 0.7f;
    const float inv_l = 1.0f / lscale;
    const float inv_a = 1.0f / 126.0f;
    float f0 = 0.f, f1 = 0.f, f2 = 0.f, f3 = 0.f;
    if (m < num[b]) {
        const int idx = indeces[(long long)b * M + m];
        const float* p = pts + ((long long)b * N + (long long)idx) * 5;
        f0 = (p[0] - cx) * inv_s;
        f1 = (p[1] - cy) * inv_s;
        f2 = (p[4] - 45.0f) * inv_a;
        f3 = (p[3] - lscale * 0.5f) * inv_l;
    }
    const long long rowoff = ((long long)b * M + m) * (long long)D;
    for (int dd = lane * 4; dd < D; dd += 64 * 4) {
        const f32x4 w0 = *(const f32x4*)(W + 0 * D + dd);
        const f32x4 w1 = *(const f32x4*)(W + 1 * D + dd);
        const f32x4 w2 = *(const f32x4*)(W + 2 * D + dd);
        const f32x4 w3 = *(const f32x4*)(W + 3 * D + dd);
        const f32x4 e  = *(const f32x4*)(emb + rowoff + dd);
        f32x4 r;
        r.x = e.x + f0 * w0.x + f1 * w1.x + f2 * w2.x + f3 * w3.x;
        r.y = e.y + f0 * w0.y + f1 * w1.y + f2 * w2.y + f3 * w3.y;
        r.z = e.z + f0 * w0.z + f1 * w1.z + f2 * w2.z + f3 * w3.z;
        r.w = e.w + f0 * w0.w + f1 * w1.w + f2 * w2.w + f3 * w3.w;
        *(f32x4*)(out + rowoff + dd) = r;
    }
}

extern "C" void kernel_launch(void* const* d_in, const int* in_sizes, int n_in,
                              void* d_out, int out_size, void* d_ws, size_t ws_size,
                              hipStream_t stream) {
    (void)n_in; (void)out_size;
    const float* emb  = (const float*)d_in[0];
    const int*   num  = (const int*)d_in[1];
    const float* pts  = (const float*)d_in[2];
    const int*   idx  = (const int*)d_in[3];
    const int*   ishp = (const int*)d_in[4];
    const float* Wm   = (const float*)d_in[5];
    float*       out  = (float*)d_out;

    const int B = in_sizes[1];
    const int D = in_sizes[5] / 4;
    const int M = (int)((long long)in_sizes[3] / B);
    const int N = (int)((long long)in_sizes[2] / ((long long)B * 5));

    const int total = B * M;                            // rows
    const size_t ws_need = (size_t)total * sizeof(f32x4);

    if (D == 256 && (M % 8) == 0 && ws_size >= ws_need) {
        f32x4* feat = (f32x4*)d_ws;
        // Pass 1: per-row features
        const int blocks1 = (total + 255) / 256;
        hipLaunchKernelGGL(posfeat_feat_kernel, dim3(blocks1), dim3(256), 0, stream,
                           num, pts, idx, ishp, feat, M, N, total);
        // Pass 2: pure stream
        const int total_tiles = total / 8;
        int blocks2 = (total_tiles + 3) / 4;
        if (blocks2 > 2048) blocks2 = 2048;             // 8 blocks/CU x 256 CU
        hipLaunchKernelGGL(posfeat_stream_kernel, dim3(blocks2), dim3(256), 0, stream,
                           emb, feat, Wm, out, total_tiles);
    } else {
        dim3 block(256);
        dim3 grid((M + 3) / 4, B);
        hipLaunchKernelGGL(posfeat_generic_kernel, grid, block, 0, stream,
                           emb, num, pts, idx, ishp, Wm, out, B, M, N, D);
    }
}

// Round 8
// 46.348 us; speedup vs baseline: 1.0728x; 1.0728x over previous
//
#include <hip/hip_runtime.h>

// PosFeatureLayer: out[b,m,d] = emb[b,m,d] + (m < num[b] ? feat(pts[b, idx[b,m]]) . W[:,d] : 0)
// Round-8: single-pass (two-pass regressed), 16 rows/tile, pipelined gather,
// persistent grid, nt stores. Effective BW at R6 was 93% of copy ceiling.

typedef float f32x4 __attribute__((ext_vector_type(4)));

#define DD 256   // fast path: D == 256 (64 lanes x f32x4)
#define ROWS 16  // rows per wave-tile

__global__ __launch_bounds__(256) void posfeat_d256_kernel(
    const float* __restrict__ emb,            // [B,M,DD]
    const int* __restrict__ num,              // [B]
    const float* __restrict__ pts,            // [B,N,5]
    const int* __restrict__ indeces,          // [B,M]
    const int* __restrict__ image_shape,      // [4] int32 (b,c,H,W)
    const float* __restrict__ W,              // [4,DD]
    float* __restrict__ out,                  // [B,M,DD]
    int M, int N, int tiles_per_b)
{
    const int lane = threadIdx.x & 63;
    const int wave = threadIdx.x >> 6;                  // 4 waves/block
    const int b = blockIdx.y;
    const int wv = blockIdx.x * 4 + wave;               // wave id within batch
    const int stride = gridDim.x * 4;

    const float h = (float)image_shape[2];
    const float w = (float)image_shape[3];
    const float inv_s  = 1.0f / (fmaxf(w, h) * 0.7f);
    const float cx = w * 0.5f, cy = h * 0.5f;
    const float lscale = sqrtf(w * w + h * h) * 0.7f;
    const float inv_l  = 1.0f / lscale;
    const float half_l = lscale * 0.5f;
    const float inv_a  = 1.0f / 126.0f;

    // W fragment in registers (L1-hit, once per wave)
    const int d0 = lane * 4;
    const f32x4 w0 = *(const f32x4*)(W + 0 * DD + d0);
    const f32x4 w1 = *(const f32x4*)(W + 1 * DD + d0);
    const f32x4 w2 = *(const f32x4*)(W + 2 * DD + d0);
    const f32x4 w3 = *(const f32x4*)(W + 3 * DD + d0);

    const int pr = lane / 5, pc = lane - pr * 5;        // pts-gather role
    const int nb = num[b];
    const long long embb = (long long)b * M;
    const long long ptsb = (long long)b * N;

    // Gather: lanes 0..15 load idx for 16 rows; pts scalars in two 8-row
    // passes of 40 lanes each (rows 0-7 -> pva, rows 8-15 -> pvb).
    auto gather = [&](int tile, int& idxv, float& pva, float& pvb) {
        idxv = -1;
        if (lane < ROWS) {
            const int m = tile * ROWS + lane;           // m < M guaranteed (M%16==0)
            if (m < nb) idxv = indeces[embb + m];
        }
        const int ira = __shfl(idxv, pr);
        const int irb = __shfl(idxv, pr + 8);
        pva = 0.f; pvb = 0.f;
        if (lane < 40) {
            if (ira >= 0) pva = pts[(ptsb + ira) * 5 + pc];
            if (irb >= 0) pvb = pts[(ptsb + irb) * 5 + pc];
        }
    };

    int tile = wv;
    int idx0 = -1; float pva0 = 0.f, pvb0 = 0.f;
    if (tile < tiles_per_b) gather(tile, idx0, pva0, pvb0);

    for (; tile < tiles_per_b; tile += stride) {
        const long long baseoff = (embb + (long long)tile * ROWS) * DD + d0;

        // Issue all emb loads first (16 independent dwordx4 -> deep MLP)
        f32x4 e[ROWS];
        #pragma unroll
        for (int r = 0; r < ROWS; ++r)
            e[r] = *(const f32x4*)(emb + baseoff + (long long)r * DD);

        // Prefetch NEXT tile's gather chain while emb loads are in flight
        const int tile2 = tile + stride;
        int idx1 = -1; float pva1 = 0.f, pvb1 = 0.f;
        if (tile2 < tiles_per_b) gather(tile2, idx1, pva1, pvb1);

        #pragma unroll
        for (int r = 0; r < ROWS; ++r) {
            const int   ir = __shfl(idx0, r);
            const float sv = (r < 8) ? pva0 : pvb0;
            const int   rr = (r < 8) ? r : (r - 8);
            const float p0 = __shfl(sv, rr * 5 + 0);
            const float p1 = __shfl(sv, rr * 5 + 1);
            const float p3 = __shfl(sv, rr * 5 + 3);
            const float p4 = __shfl(sv, rr * 5 + 4);
            float f0 = 0.f, f1 = 0.f, f2 = 0.f, f3 = 0.f;
            if (ir >= 0) {
                f0 = (p0 - cx) * inv_s;
                f1 = (p1 - cy) * inv_s;
                f2 = (p4 - 45.0f) * inv_a;
                f3 = (p3 - half_l) * inv_l;
            }
            f32x4 o;
            o.x = e[r].x + f0 * w0.x + f1 * w1.x + f2 * w2.x + f3 * w3.x;
            o.y = e[r].y + f0 * w0.y + f1 * w1.y + f2 * w2.y + f3 * w3.y;
            o.z = e[r].z + f0 * w0.z + f1 * w1.z + f2 * w2.z + f3 * w3.z;
            o.w = e[r].w + f0 * w0.w + f1 * w1.w + f2 * w2.w + f3 * w3.w;
            __builtin_nontemporal_store(o, (f32x4*)(out + baseoff + (long long)r * DD));
        }
        idx0 = idx1; pva0 = pva1; pvb0 = pvb1;
    }
}

// Generic fallback (any D multiple of 4): 1 row/wave.
__global__ __launch_bounds__(256) void posfeat_generic_kernel(
    const float* __restrict__ emb, const int* __restrict__ num,
    const float* __restrict__ pts, const int* __restrict__ indeces,
    const int* __restrict__ image_shape, const float* __restrict__ W,
    float* __restrict__ out, int B, int M, int N, int D)
{
    const int lane = threadIdx.x & 63;
    const int wave = threadIdx.x >> 6;
    const int m = blockIdx.x * 4 + wave;
    const int b = blockIdx.y;
    if (m >= M) return;
    const float h = (float)image_shape[2];
    const float w = (float)image_shape[3];
    const float inv_s = 1.0f / (fmaxf(w, h) * 0.7f);
    const float cx = w * 0.5f, cy = h * 0.5f;
    const float lscale = sqrtf(w * w + h * h) * 0.7f;
    const float inv_l = 1.0f / lscale;
    const float inv_a = 1.0f / 126.0f;
    float f0 = 0.f, f1 = 0.f, f2 = 0.f, f3 = 0.f;
    if (m < num[b]) {
        const int idx = indeces[(long long)b * M + m];
        const float* p = pts + ((long long)b * N + (long long)idx) * 5;
        f0 = (p[0] - cx) * inv_s;
        f1 = (p[1] - cy) * inv_s;
        f2 = (p[4] - 45.0f) * inv_a;
        f3 = (p[3] - lscale * 0.5f) * inv_l;
    }
    const long long rowoff = ((long long)b * M + m) * (long long)D;
    for (int dd = lane * 4; dd < D; dd += 64 * 4) {
        const f32x4 w0 = *(const f32x4*)(W + 0 * D + dd);
        const f32x4 w1 = *(const f32x4*)(W + 1 * D + dd);
        const f32x4 w2 = *(const f32x4*)(W + 2 * D + dd);
        const f32x4 w3 = *(const f32x4*)(W + 3 * D + dd);
        const f32x4 e  = *(const f32x4*)(emb + rowoff + dd);
        f32x4 r;
        r.x = e.x + f0 * w0.x + f1 * w1.x + f2 * w2.x + f3 * w3.x;
        r.y = e.y + f0 * w0.y + f1 * w1.y + f2 * w2.y + f3 * w3.y;
        r.z = e.z + f0 * w0.z + f1 * w1.z + f2 * w2.z + f3 * w3.z;
        r.w = e.w + f0 * w0.w + f1 * w1.w + f2 * w2.w + f3 * w3.w;
        *(f32x4*)(out + rowoff + dd) = r;
    }
}

extern "C" void kernel_launch(void* const* d_in, const int* in_sizes, int n_in,
                              void* d_out, int out_size, void* d_ws, size_t ws_size,
                              hipStream_t stream) {
    (void)n_in; (void)d_ws; (void)ws_size; (void)out_size;
    const float* emb  = (const float*)d_in[0];
    const int*   num  = (const int*)d_in[1];
    const float* pts  = (const float*)d_in[2];
    const int*   idx  = (const int*)d_in[3];
    const int*   ishp = (const int*)d_in[4];
    const float* Wm   = (const float*)d_in[5];
    float*       out  = (float*)d_out;

    const int B = in_sizes[1];
    const int D = in_sizes[5] / 4;
    const int M = (int)((long long)in_sizes[3] / B);
    const int N = (int)((long long)in_sizes[2] / ((long long)B * 5));

    if (D == 256 && (M % ROWS) == 0) {
        const int tiles_per_b = M / ROWS;
        // 2048 blocks total (8/CU x 256 CU): x = blocks per batch, y = batch
        int bx = 2048 / B; if (bx < 1) bx = 1;
        if (bx * 4 > tiles_per_b) bx = (tiles_per_b + 3) / 4;
        hipLaunchKernelGGL(posfeat_d256_kernel, dim3(bx, B), dim3(256), 0, stream,
                           emb, num, pts, idx, ishp, Wm, out, M, N, tiles_per_b);
    } else {
        dim3 block(256);
        dim3 grid((M + 3) / 4, B);
        hipLaunchKernelGGL(posfeat_generic_kernel, grid, block, 0, stream,
                           emb, num, pts, idx, ishp, Wm, out, B, M, N, D);
    }
}